// Round 3
// baseline (605.082 us; speedup 1.0000x reference)
//
#include <hip/hip_runtime.h>

// ---------------------------------------------------------------------------
// ExpertParallelMoE: top-1 routing, E=8 experts, D=1024, H=4096, C=2048,
// N = 4*2048 = 8192 tokens. bf16 MFMA grouped-GEMM implementation.
// R3: GEMM mainloop -> T3 "minimum 2-phase" explicit LDS double-buffer
// (prefetch next K-tile during MFMA, one barrier per K-step), BK=64,
// XOR-chunk swizzle (linear gload_lds dest + inverse-swizzled source +
// swizzled ds_read) to kill the 16-way bank alias. Vectorized transposes.
// T1 XCD expert-chunk swizzle kept from R2 (FETCH dropped to compulsory).
// ---------------------------------------------------------------------------

#define N_TOK   8192
#define DMODEL  1024
#define HDIM    4096
#define NEXP    8
#define CAP     2048
#define MAXROWS 9216   // sum of per-expert 128-padded counts <= 8192 + 8*127

typedef float  f32x4  __attribute__((ext_vector_type(4)));
typedef __bf16 bf16x8 __attribute__((ext_vector_type(8)));

typedef void __attribute__((address_space(1))) as1_void;
typedef void __attribute__((address_space(3))) as3_void;

__device__ __forceinline__ void async_copy16(void* lds, const void* g) {
    __builtin_amdgcn_global_load_lds((as1_void*)g, (as3_void*)lds, 16, 0, 0);
}

__device__ __forceinline__ unsigned short f2bf(float f) {
    unsigned u = __float_as_uint(f);
    unsigned r = (u + 0x7fffu + ((u >> 16) & 1u)) >> 16;
    return (unsigned short)r;
}

// ---------------------------------------------------------------------------
// 1) Gating: logits = x @ Wg + bg, argmax (first index wins on ties).
//    fp64 accumulation so ordering matches the fp64 numpy reference.
// ---------------------------------------------------------------------------
__global__ __launch_bounds__(256) void gate_kernel(
    const float* __restrict__ x, const float* __restrict__ Wg,
    const float* __restrict__ bg, int* __restrict__ route)
{
    const int wave = threadIdx.x >> 6, lane = threadIdx.x & 63;
    const int tok = blockIdx.x * 4 + wave;
    const float* xr = x + (size_t)tok * DMODEL;
    double acc[8];
#pragma unroll
    for (int e = 0; e < 8; ++e) acc[e] = 0.0;
    for (int i = 0; i < DMODEL / 64; ++i) {
        const int d = i * 64 + lane;
        const double xv = (double)xr[d];
        const float* wr = Wg + (size_t)d * 8;
#pragma unroll
        for (int e = 0; e < 8; ++e) acc[e] += xv * (double)wr[e];
    }
#pragma unroll
    for (int e = 0; e < 8; ++e) {
        double v = acc[e];
#pragma unroll
        for (int off = 32; off > 0; off >>= 1) v += __shfl_down(v, off, 64);
        acc[e] = v;
    }
    if (lane == 0) {
        double bv = acc[0] + (double)bg[0];
        int bi = 0;
#pragma unroll
        for (int e = 1; e < 8; ++e) {
            double v = acc[e] + (double)bg[e];
            if (v > bv) { bv = v; bi = e; }
        }
        route[tok] = bi;
    }
}

// ---------------------------------------------------------------------------
// 2) Scan (single block): token-order positions per expert, capacity clamp,
//    per-expert 128-padded row bases, and row -> token map.
//    meta layout (ints): [0..7]=cnt  [8..15]=padded  [16..23]=rowbase  [24]=total
// ---------------------------------------------------------------------------
__global__ __launch_bounds__(256) void scan_kernel(
    const int* __restrict__ route, int* __restrict__ tokrow,
    int* __restrict__ meta)
{
    __shared__ int hist[256][8];
    __shared__ int cntS[8];
    __shared__ int rowbaseS[8];
    const int tid = threadIdx.x;
    for (int i = tid; i < MAXROWS; i += 256) tokrow[i] = -1;
    const int t0 = tid * 32;
    int r[32];
#pragma unroll
    for (int i = 0; i < 32; ++i) r[i] = route[t0 + i];
    int loc[8];
#pragma unroll
    for (int e = 0; e < 8; ++e) loc[e] = 0;
#pragma unroll
    for (int i = 0; i < 32; ++i) {
#pragma unroll
        for (int e = 0; e < 8; ++e) loc[e] += (r[i] == e) ? 1 : 0;
    }
#pragma unroll
    for (int e = 0; e < 8; ++e) hist[tid][e] = loc[e];
    __syncthreads();
    if (tid < 8) {
        int run = 0;
        for (int t = 0; t < 256; ++t) { int v = hist[t][tid]; hist[t][tid] = run; run += v; }
        meta[tid] = run;
        cntS[tid] = run;
    }
    __syncthreads();
    if (tid == 0) {
        int rb = 0;
#pragma unroll
        for (int e = 0; e < 8; ++e) {
            int c = cntS[e]; if (c > CAP) c = CAP;
            int p = (c + 127) & ~127;
            meta[8 + e] = p;
            meta[16 + e] = rb;
            rowbaseS[e] = rb;
            rb += p;
        }
        meta[24] = rb;
    }
    __syncthreads();
    int base[8];
#pragma unroll
    for (int e = 0; e < 8; ++e) base[e] = hist[tid][e];
#pragma unroll
    for (int i = 0; i < 32; ++i) {
        const int e = r[i];
        const int p = base[e]++;
        if (p < CAP) tokrow[rowbaseS[e] + p] = t0 + i;
    }
}

// ---------------------------------------------------------------------------
// 3) Dispatch: xg[row][:] = bf16(x[token][:]) (zeros for padding rows).
// ---------------------------------------------------------------------------
__global__ __launch_bounds__(256) void dispatch_kernel(
    const float* __restrict__ x, const int* __restrict__ tokrow,
    unsigned short* __restrict__ xg)
{
    const int row = blockIdx.x;
    const int tok = tokrow[row];
    const int d = threadIdx.x * 4;
    float4 v = make_float4(0.f, 0.f, 0.f, 0.f);
    if (tok >= 0) v = *(const float4*)(x + (size_t)tok * DMODEL + d);
    ushort4 o;
    o.x = f2bf(v.x); o.y = f2bf(v.y); o.z = f2bf(v.z); o.w = f2bf(v.w);
    *(ushort4*)(xg + (size_t)row * DMODEL + d) = o;
}

// ---------------------------------------------------------------------------
// 4) Weight transpose+cast: in (E,R,C) f32 row-major -> out (E,C,R) bf16.
//    Tile 64x64, block 256. float4 global reads (16B/lane), conflict-free
//    [64][65] LDS (scalar ops land 2-way max = free), ushort4 stores give
//    full 128B write segments per 16-lane group.
// ---------------------------------------------------------------------------
__global__ __launch_bounds__(256) void transpose_cast_kernel(
    const float* __restrict__ in, unsigned short* __restrict__ out,
    int R, int C)
{
    __shared__ float t[64][65];
    const size_t base = (size_t)blockIdx.z * R * C;
    const int c0 = blockIdx.x * 64, r0 = blockIdx.y * 64;
    const int tid = threadIdx.x;
    const int rl = tid >> 4;          // 0..15
    const int cl = (tid & 15) * 4;    // 0,4,...,60
#pragma unroll
    for (int i = 0; i < 4; ++i) {
        const int r = rl + i * 16;
        const float4 v = *(const float4*)(in + base + (size_t)(r0 + r) * C + c0 + cl);
        t[r][cl] = v.x; t[r][cl + 1] = v.y; t[r][cl + 2] = v.z; t[r][cl + 3] = v.w;
    }
    __syncthreads();
#pragma unroll
    for (int i = 0; i < 4; ++i) {
        const int c = rl + i * 16;
        ushort4 o;
        o.x = f2bf(t[cl + 0][c]);
        o.y = f2bf(t[cl + 1][c]);
        o.z = f2bf(t[cl + 2][c]);
        o.w = f2bf(t[cl + 3][c]);
        *(ushort4*)(out + base + (size_t)(c0 + c) * R + r0 + cl) = o;
    }
}

// ---------------------------------------------------------------------------
// Shared MFMA main loop, T3 minimum-2-phase. C_tile(128x128) += A(128xK)*B^T.
// BK=64; LDS = 2 buffers x (A 16KB + B 16KB) = 64KB. Per K-step: issue next
// tile's 8 global_load_lds into the alternate buffer, then ds_read+MFMA the
// current one, then ONE __syncthreads (drains vmcnt/lgkmcnt) -> loads stay
// in flight under the 32-MFMA compute phase.
// Swizzle (rule #21, m201 pattern): gload_lds dest is linear; the global
// SOURCE 16B-chunk index is XOR'd with (row&7), and ds_read applies the same
// XOR -> involution. Breaks the 16-way bank alias of the 128B row stride:
// 16 lanes spread over 8 chunk slots = 2-way (free).
// ---------------------------------------------------------------------------
__device__ __forceinline__ void stage_tile(
    const unsigned short* __restrict__ A,
    const unsigned short* __restrict__ B,
    int K, int tid, char* bufA, char* bufB, int k0)
{
#pragma unroll
    for (int i = 0; i < 4; ++i) {
        const int c = tid + i * 256;            // 16B chunk 0..1023
        const int row = c >> 3;                 // 0..127
        const int g8 = ((c & 7) ^ (row & 7)) * 8;   // source-side XOR swizzle
        async_copy16(bufA + (size_t)c * 16, A + (size_t)row * K + k0 + g8);
    }
#pragma unroll
    for (int i = 0; i < 4; ++i) {
        const int c = tid + i * 256;
        const int row = c >> 3;
        const int g8 = ((c & 7) ^ (row & 7)) * 8;
        async_copy16(bufB + (size_t)c * 16, B + (size_t)row * K + k0 + g8);
    }
}

__device__ __forceinline__ void compute_tile(
    const char* bufA, const char* bufB,
    int wm, int wn, int l16, int quad, f32x4 acc[4][4])
{
#pragma unroll
    for (int ks = 0; ks < 2; ++ks) {
        // logical 16B chunk within row = ks*4+quad; apply the same XOR
        const int sc = ((ks * 4 + quad) ^ (l16 & 7)) * 16;
        bf16x8 a[4], b[4];
#pragma unroll
        for (int mi = 0; mi < 4; ++mi)
            a[mi] = *(const bf16x8*)(bufA + (wm + mi * 16 + l16) * 128 + sc);
#pragma unroll
        for (int ni = 0; ni < 4; ++ni)
            b[ni] = *(const bf16x8*)(bufB + (wn + ni * 16 + l16) * 128 + sc);
#pragma unroll
        for (int mi = 0; mi < 4; ++mi)
#pragma unroll
            for (int ni = 0; ni < 4; ++ni)
                acc[mi][ni] = __builtin_amdgcn_mfma_f32_16x16x32_bf16(
                    a[mi], b[ni], acc[mi][ni], 0, 0, 0);
    }
}

__device__ __forceinline__ void mfma_mainloop(
    const unsigned short* __restrict__ A,
    const unsigned short* __restrict__ B,
    int K, int tid, char* smem, f32x4 acc[4][4])
{
    const int wave = tid >> 6, lane = tid & 63;
    const int quad = lane >> 4, l16 = lane & 15;
    const int wm = (wave & 1) * 64, wn = (wave >> 1) * 64;
    char* A0 = smem;
    char* B0 = smem + 16384;
    char* A1 = smem + 32768;
    char* B1 = smem + 49152;

    stage_tile(A, B, K, tid, A0, B0, 0);
    __syncthreads();                       // drain prologue loads
    const int nIter = K >> 6;
    for (int it = 0; it < nIter; ++it) {
        const bool odd = (it & 1) != 0;
        if (it + 1 < nIter)
            stage_tile(A, B, K, tid, odd ? A0 : A1, odd ? B0 : B1,
                       (it + 1) << 6);     // prefetch BEFORE compute
        compute_tile(odd ? A1 : A0, odd ? B1 : B0, wm, wn, l16, quad, acc);
        __syncthreads();                   // one vmcnt(0)+barrier per K-step
    }
}

// ---------------------------------------------------------------------------
// 5) GEMM1: h = relu(xg @ W1[e] + b1[e]) -> bf16 hbuf[row][HDIM].
//    T1 swizzle: 512 blocks/XCD = one expert per XCD, mtile-fastest.
//    LDS: 64KB staging; epilogue hl reuses the first 32KB after the final
//    mainloop barrier.
// ---------------------------------------------------------------------------
__global__ __launch_bounds__(256) void gemm1_kernel(
    const unsigned short* __restrict__ xg,
    const unsigned short* __restrict__ wb,    // (E, HDIM, DMODEL) bf16
    const float* __restrict__ b1,             // (E, HDIM)
    unsigned short* __restrict__ hbuf,        // (rows, HDIM) bf16
    const int* __restrict__ meta)
{
    // grid = (32, 16, 8) -> lin in [0,4096); chunk 512 per XCD
    const int lin = blockIdx.x + 32 * (blockIdx.y + 16 * blockIdx.z);
    const int work = (lin & 7) * 512 + (lin >> 3);
    const int e = work >> 9;
    const int rem = work & 511;
    const int mtile = rem & 15, ntile = rem >> 4;
    if (mtile * 128 >= meta[8 + e]) return;
    const int row0 = meta[16 + e] + mtile * 128;
    const int tid = threadIdx.x;

    __shared__ __align__(16) char lds[65536];

    f32x4 acc[4][4];
#pragma unroll
    for (int mi = 0; mi < 4; ++mi)
#pragma unroll
        for (int ni = 0; ni < 4; ++ni)
#pragma unroll
            for (int r = 0; r < 4; ++r) acc[mi][ni][r] = 0.0f;

    mfma_mainloop(xg + (size_t)row0 * DMODEL,
                  wb + ((size_t)e * HDIM + (size_t)ntile * 128) * DMODEL,
                  DMODEL, tid, lds, acc);

    unsigned short* hl = (unsigned short*)lds;   // 128*128 bf16 = 32KB
    const int wave = tid >> 6, lane = tid & 63;
    const int quad = lane >> 4, l16 = lane & 15;
    const int wm = (wave & 1) * 64, wn = (wave >> 1) * 64;
    const float* bias = b1 + (size_t)e * HDIM + (size_t)ntile * 128;
#pragma unroll
    for (int mi = 0; mi < 4; ++mi)
#pragma unroll
        for (int ni = 0; ni < 4; ++ni) {
            const int cc = wn + ni * 16 + l16;
            const float bv = bias[cc];
#pragma unroll
            for (int r = 0; r < 4; ++r) {
                const int rr = wm + mi * 16 + quad * 4 + r;
                hl[rr * 128 + cc] = f2bf(fmaxf(acc[mi][ni][r] + bv, 0.0f));
            }
        }
    __syncthreads();
#pragma unroll
    for (int i = 0; i < 8; ++i) {
        const int c = tid + i * 256;       // 16B chunk index
        const int m = c >> 4;
        const int nb = (c & 15) * 8;
        *(int4*)(hbuf + (size_t)(row0 + m) * HDIM + (size_t)ntile * 128 + nb) =
            *(const int4*)(hl + m * 128 + nb);
    }
}

// ---------------------------------------------------------------------------
// 6) GEMM2: out[token] = h @ W2[e] + b2[e], scattered via tokrow.
//    T1 swizzle: 128 blocks/XCD = one expert per XCD, mtile-fastest.
// ---------------------------------------------------------------------------
__global__ __launch_bounds__(256) void gemm2_kernel(
    const unsigned short* __restrict__ hbuf,
    const unsigned short* __restrict__ wb,    // (E, DMODEL, HDIM) bf16
    const float* __restrict__ b2,             // (E, DMODEL)
    const int* __restrict__ tokrow,
    float* __restrict__ out,
    const int* __restrict__ meta)
{
    // grid = (8, 16, 8) -> lin in [0,1024); chunk 128 per XCD
    const int lin = blockIdx.x + 8 * (blockIdx.y + 16 * blockIdx.z);
    const int work = (lin & 7) * 128 + (lin >> 3);
    const int e = work >> 7;
    const int rem = work & 127;
    const int mtile = rem & 15, ntile = rem >> 4;
    if (mtile * 128 >= meta[8 + e]) return;
    const int row0 = meta[16 + e] + mtile * 128;
    const int tid = threadIdx.x;

    __shared__ __align__(16) char lds[65536];

    f32x4 acc[4][4];
#pragma unroll
    for (int mi = 0; mi < 4; ++mi)
#pragma unroll
        for (int ni = 0; ni < 4; ++ni)
#pragma unroll
            for (int r = 0; r < 4; ++r) acc[mi][ni][r] = 0.0f;

    mfma_mainloop(hbuf + (size_t)row0 * HDIM,
                  wb + ((size_t)e * DMODEL + (size_t)ntile * 128) * HDIM,
                  HDIM, tid, lds, acc);

    const int wave = tid >> 6, lane = tid & 63;
    const int quad = lane >> 4, l16 = lane & 15;
    const int wm = (wave & 1) * 64, wn = (wave >> 1) * 64;
#pragma unroll
    for (int mi = 0; mi < 4; ++mi) {
#pragma unroll
        for (int r = 0; r < 4; ++r) {
            const int rowl = wm + mi * 16 + quad * 4 + r;
            const int tok = tokrow[row0 + rowl];
            if (tok >= 0) {
#pragma unroll
                for (int ni = 0; ni < 4; ++ni) {
                    const int col = ntile * 128 + wn + ni * 16 + l16;
                    out[(size_t)tok * DMODEL + col] =
                        acc[mi][ni][r] + b2[(size_t)e * DMODEL + col];
                }
            }
        }
    }
}

// ---------------------------------------------------------------------------
// Launch. Workspace layout (bytes):
//   [0,32K)        route (8192 int)
//   [32K,69632)    tokrow (9216 int)
//   [69632,69732)  meta (25 int)
//   [128K, ~19MB)  xg    (9216 x 1024 bf16)
//   [20MB, ~92MB)  hbuf  (9216 x 4096 bf16)
//   [96MB, 160MB)  wb    (64MB, reused: W1^T bf16 for gemm1, then W2^T)
// ---------------------------------------------------------------------------
extern "C" void kernel_launch(void* const* d_in, const int* in_sizes, int n_in,
                              void* d_out, int out_size, void* d_ws, size_t ws_size,
                              hipStream_t stream) {
    (void)in_sizes; (void)n_in; (void)out_size; (void)ws_size;
    const float* x  = (const float*)d_in[0];
    const float* Wg = (const float*)d_in[1];
    const float* bg = (const float*)d_in[2];
    const float* W1 = (const float*)d_in[3];
    const float* b1 = (const float*)d_in[4];
    const float* W2 = (const float*)d_in[5];
    const float* b2 = (const float*)d_in[6];
    float* out = (float*)d_out;
    char* ws = (char*)d_ws;

    int* route  = (int*)ws;
    int* tokrow = (int*)(ws + 32768);
    int* meta   = (int*)(ws + 69632);
    unsigned short* xg   = (unsigned short*)(ws + (size_t)131072);
    unsigned short* hbuf = (unsigned short*)(ws + (size_t)20 * 1024 * 1024);
    unsigned short* wb   = (unsigned short*)(ws + (size_t)96 * 1024 * 1024);

    hipMemsetAsync(d_out, 0, (size_t)N_TOK * DMODEL * sizeof(float), stream);

    gate_kernel<<<N_TOK / 4, 256, 0, stream>>>(x, Wg, bg, route);
    scan_kernel<<<1, 256, 0, stream>>>(route, tokrow, meta);
    dispatch_kernel<<<MAXROWS, 256, 0, stream>>>(x, tokrow, xg);

    // W1 (E, R=1024, C=4096) -> wb (E, 4096, 1024) bf16
    transpose_cast_kernel<<<dim3(HDIM / 64, DMODEL / 64, NEXP), 256, 0, stream>>>(
        W1, wb, DMODEL, HDIM);
    gemm1_kernel<<<dim3(HDIM / 128, 16, NEXP), 256, 0, stream>>>(
        xg, wb, b1, hbuf, meta);

    // W2 (E, R=4096, C=1024) -> wb (E, 1024, 4096) bf16  (reuses wb)
    transpose_cast_kernel<<<dim3(DMODEL / 64, HDIM / 64, NEXP), 256, 0, stream>>>(
        W2, wb, HDIM, DMODEL);
    gemm2_kernel<<<dim3(DMODEL / 128, 16, NEXP), 256, 0, stream>>>(
        hbuf, wb, b2, tokrow, out, meta);
}